// Round 21
// baseline (132.668 us; speedup 1.0000x reference)
//
#include <hip/hip_runtime.h>

#define B 64
#define N 1024
#define E 16384
#define WPR 32          // words per adjacency row = N/32
#define NITER 5
#define CSR_SLOTS (E + N)   // even-aligned per-node alloc: <=1 pad slot/node
#define CH_ROWS 384
#define CH_WORDS (CH_ROWS * WPR)    // 12288 u32 = 48 KB chunk
#define NCHUNK 3

// ---- workspace layout (bytes) ---- (NO memset: feats/diag fully stored
// before any read; harness 0xAA poison harmless)
#define FEATS_OFF 0
#define DIAG_OFF  ((size_t)B * N * 4)

// R21 = R20 (measured-best) + two shavings:
//  (1) B1/B2 -> one barrier: wave leaders LDS-atomicMin/Max the monotone
//      uint key (16 same-addr atomics ~150cyc vs barrier+combine ~600cyc);
//      bucket map on uint stays order-preserving -> identical ranks.
//  (2) self-cleaning chunk zero: bulk-zero chunk 0 only; capture threads
//      write zeros back after reading their row (exactly covers the 48KB).
__global__ void __launch_bounds__(1024) wl_mega_k(const int* __restrict__ src,
                                                  const int* __restrict__ dstp,
                                                  const int* __restrict__ lab0,
                                                  const float* __restrict__ hw,
                                                  unsigned int* __restrict__ feats,
                                                  float* __restrict__ diag) {
    __shared__ union {
        unsigned int chunk[CH_WORDS];               // Phase A1: 48KB bitmask tile
        struct {
            unsigned short nbr[CSR_SLOTS];          // Phase A2/B: 34.8KB CSR
            struct {                                // Phase B: rank arrays 16KB
                int hist[N];
                int scan[N];
                unsigned int grp[N];
                int flag[N];
            } pb;
        } s;
    } u;
    __shared__ int s_lab[N + 2];                    // +sentinel slot (=0)
    __shared__ unsigned int s_feats[N];
    __shared__ int s_wsum[16];
    __shared__ int s_kp[16];
    __shared__ unsigned int s_gmnU, s_gmxU;
    __shared__ int s_K;
    __shared__ int s_anytie;
    int b = blockIdx.x, t = threadIdx.x;
    int lane = t & 63, w = t >> 6;

    // ---- Phase A0: edges + labels to registers/LDS ----
    const int* sg = src + (size_t)b * E;
    const int* dg_ = dstp + (size_t)b * E;
    int es[16], ed[16];
#pragma unroll
    for (int k = 0; k < 16; ++k) {                  // coalesced, 1 block/graph
        es[k] = sg[t + k * 1024];
        ed[k] = dg_[t + k * 1024];
    }
    int l0 = lab0[(size_t)b * N + t];
    s_lab[t] = l0;
    s_feats[t] = 0;
    if (t == 0) { s_lab[N] = 0; s_anytie = 0; s_gmnU = ~0u; s_gmxU = 0u; }
    __syncthreads();                                        // P0
    // init label bincount (labels < 16) via ballot
#pragma unroll
    for (int v = 0; v < 16; ++v) {
        unsigned long long m = __ballot(l0 == v);
        if (lane == v) {
            int c = __popcll(m);
            if (c) atomicAdd(&s_feats[v], (unsigned)c);
        }
    }

    // ---- Phase A1: 3-chunk LDS bitmask build (swizzled), row -> r[8] ----
    uint4 r[8];
#pragma unroll 1
    for (int c = 0; c < NCHUNK; ++c) {
        int base = c * CH_ROWS;
        if (c == 0) {                               // bulk zero only once:
#pragma unroll
            for (int k = 0; k < 3; ++k)             // later chunks self-clean
                ((uint4*)u.chunk)[t + k * 1024] = make_uint4(0, 0, 0, 0);
            __syncthreads();                                // C1 (chunk 0 only)
        }
#pragma unroll
        for (int k = 0; k < 16; ++k) {
            int rr = es[k] - base;
            if ((unsigned)rr < (unsigned)CH_ROWS) {
                int wlog = ed[k] >> 5;                      // logical word 0..31
                int g = wlog >> 2;                          // logical group 0..7
                int p = (g + rr) & 7;                       // swizzled slot
                atomicOr(&u.chunk[rr * WPR + p * 4 + (wlog & 3)],
                         1u << (ed[k] & 31));
            }
        }
        __syncthreads();                                    // C2
        int rl = t - base;
        if ((unsigned)rl < (unsigned)CH_ROWS) {             // own row lives here
            uint4* row4 = (uint4*)(u.chunk + rl * WPR);
#pragma unroll
            for (int g = 0; g < 8; ++g) {
                int p = (g + rl) & 7;
                r[g] = row4[p];                             // conflict-free
                row4[p] = make_uint4(0, 0, 0, 0);           // self-clean
            }
        }
        __syncthreads();                                    // C3
    }

    // ---- Phase A2: deg/alloc/K/CSR starts + pack ----
    int dg = 0;
#pragma unroll
    for (int k = 0; k < 8; ++k)
        dg += __popc(r[k].x) + __popc(r[k].y) + __popc(r[k].z) + __popc(r[k].w);
    int alloc = (dg + 1) & ~1;                      // even per-node CSR alloc

    int f = alloc;                                  // wave scan of alloc
#pragma unroll
    for (int d2 = 1; d2 < 64; d2 <<= 1) {
        int v = __shfl_up(f, d2);
        if (lane >= d2) f += v;
    }
    int km = dg;
#pragma unroll
    for (int o = 32; o > 0; o >>= 1) km = max(km, __shfl_down(km, o));
    if (lane == 63) s_wsum[w] = f;
    if (lane == 0)  s_kp[w] = km;
    __syncthreads();                                        // A1
    if (w == 0) {                                   // wave0 shfl combine
        int orig = (lane < 16) ? s_wsum[lane] : 0;
        int v = orig;
#pragma unroll
        for (int d2 = 1; d2 < 16; d2 <<= 1) {
            int uu = __shfl_up(v, d2);
            if (lane >= d2) v += uu;
        }
        if (lane < 16) s_wsum[lane] = v - orig;     // exclusive wave base
        int kk = (lane < 16) ? s_kp[lane] : 0;
#pragma unroll
        for (int m2 = 8; m2 >= 1; m2 >>= 1) kk = max(kk, __shfl_xor(kk, m2));
        if (lane == 0) s_K = kk;
    }
    __syncthreads();                                        // A2
    int start = (f - alloc) + s_wsum[w];            // even => u32-aligned
    u.s.pb.hist[t] = 0;                             // aliases chunk: re-init
    u.s.pb.flag[t] = 0;

    // pack own row's set bits ONCE -> u16 list; pad odd deg with sentinel N
    {
        int idx = start;
#pragma unroll
        for (int k = 0; k < 8; ++k) {
            unsigned int wv[4] = { r[k].x, r[k].y, r[k].z, r[k].w };
#pragma unroll
            for (int c2 = 0; c2 < 4; ++c2) {
                unsigned int word = wv[c2];
                int bb = (k * 4 + c2) << 5;
                while (word) {
                    int j = __ffs(word) - 1;
                    word &= word - 1;
                    u.s.nbr[idx++] = (unsigned short)(bb + j);
                }
            }
        }
        if (dg & 1) u.s.nbr[idx] = (unsigned short)N;   // sentinel -> adds 0
    }
    float Kf = (float)s_K;
    float w0 = hw[0], w1 = hw[1];
    int pairs = alloc >> 1;
    int pstart = start >> 1;
    __syncthreads();                                        // A3

    // ---- Phase B: 5 WL iterations (R12-proven machinery) ----
    for (int it = 0; it < NITER; ++it) {
        int s = 0;
        const unsigned int* nbr32 = (const unsigned int*)u.s.nbr;
        for (int k = 0; k < pairs; ++k) {
            unsigned int pr = nbr32[pstart + k];
            s += s_lab[pr & 0xFFFFu] + s_lab[pr >> 16];
        }
        float t1 = __fmul_rn(__fmul_rn(Kf, w0), (float)s_lab[t]);
        float t2 = __fmul_rn(w1, __fsub_rn(__fadd_rn((float)s, (float)dg), Kf));
        float h  = __fadd_rn(t1, t2);
        // monotone float->uint (equal floats <-> equal keys; -0 == +0)
        unsigned int bits = __float_as_uint(h);
        if (bits == 0x80000000u) bits = 0u;
        unsigned int ikey = (bits & 0x80000000u) ? ~bits : (bits | 0x80000000u);

        // block min/max of ikey: wave shfl reduce + 16 leader LDS atomics
        unsigned int mnU = ikey, mxU = ikey;
#pragma unroll
        for (int o = 32; o > 0; o >>= 1) {
            mnU = min(mnU, (unsigned)__shfl_down((int)mnU, o));
            mxU = max(mxU, (unsigned)__shfl_down((int)mxU, o));
        }
        if (lane == 0) { atomicMin(&s_gmnU, mnU); atomicMax(&s_gmxU, mxU); }
        __syncthreads();                                    // B1 (was B1+B2)
        unsigned int gmn = s_gmnU;
        unsigned int span = s_gmxU - gmn;
        float scale = span ? (1023.0f / (float)span) : 0.f;
        int bucket = min((int)((float)(ikey - gmn) * scale), 1023); // monotone
        int off_in = atomicAdd(&u.s.pb.hist[bucket], 1);
        __syncthreads();                                    // B3

        f = u.s.pb.hist[t];
#pragma unroll
        for (int d2 = 1; d2 < 64; d2 <<= 1) {
            int v = __shfl_up(f, d2);
            if (lane >= d2) f += v;
        }
        if (lane == 63) s_wsum[w] = f;
        __syncthreads();                                    // B4
        if (w == 0) {                                // wave0 shfl combine
            int orig = (lane < 16) ? s_wsum[lane] : 0;
            int v = orig;
#pragma unroll
            for (int d2 = 1; d2 < 16; d2 <<= 1) {
                int uu = __shfl_up(v, d2);
                if (lane >= d2) v += uu;
            }
            if (lane < 16) s_wsum[lane] = v - orig;  // exclusive
        }
        __syncthreads();                                    // B5
        u.s.pb.scan[t] = f + s_wsum[w];
        __syncthreads();                                    // B6

        int bs = u.s.pb.scan[bucket] - u.s.pb.hist[bucket];
        int be = u.s.pb.scan[bucket];
        u.s.pb.grp[bs + off_in] = ikey;
        __syncthreads();                                    // B7

        int c = bs;                 // lower buckets strictly less (monotone map)
        int eq = 0;
        for (int k = bs; k < be; ++k) {
            unsigned int g = u.s.pb.grp[k];
            c += (g < ikey);
            eq += (g == ikey);
        }
        if (eq > 1) s_anytie = it + 1;  // sentinel: stale iters self-invalidate
        u.s.pb.hist[t] = 0;             // re-zero for next iter
        __syncthreads();                                    // B8
        if (t == 0) { s_gmnU = ~0u; s_gmxU = 0u; }  // reset for next iter

        int rank;
        if (s_anytie != it + 1) {
            rank = c;                   // distinct keys: c IS the dense rank
            s_lab[t] = rank;
            s_feats[rank] += 1u;        // permutation -> conflict-free
        } else {
            u.s.pb.flag[c] = 1;         // class start (same class -> same c)
            __syncthreads();                                // T1
            int f2 = u.s.pb.flag[t];
#pragma unroll
            for (int d2 = 1; d2 < 64; d2 <<= 1) {
                int v = __shfl_up(f2, d2);
                if (lane >= d2) f2 += v;
            }
            if (lane == 63) s_wsum[w] = f2;
            __syncthreads();                                // T2
            if (w == 0) {                            // wave0 shfl combine
                int orig = (lane < 16) ? s_wsum[lane] : 0;
                int v = orig;
#pragma unroll
                for (int d2 = 1; d2 < 16; d2 <<= 1) {
                    int uu = __shfl_up(v, d2);
                    if (lane >= d2) v += uu;
                }
                if (lane < 16) s_wsum[lane] = v - orig;
            }
            __syncthreads();                                // T3
            u.s.pb.scan[t] = f2 + s_wsum[w];
            u.s.pb.flag[t] = 0;         // own flag consumed above
            __syncthreads();                                // T4
            rank = u.s.pb.scan[c] - 1;
            s_lab[t] = rank;
            atomicAdd(&s_feats[rank], 1u);
        }
        __syncthreads();                                    // B9
    }

    // ---- Phase C: feats out + fused diag[b] (int exact) ----
    unsigned int fv = s_feats[t];
    feats[(size_t)b * N + t] = fv;
    int sq = (int)(fv * fv);
#pragma unroll
    for (int o = 32; o > 0; o >>= 1) sq += __shfl_down(sq, o);
    if (lane == 0) s_wsum[w] = sq;
    __syncthreads();
    if (t == 0) {
        int tot = 0;
#pragma unroll
        for (int k = 0; k < 16; ++k) tot += s_wsum[k];
        diag[b] = (float)tot;
    }
}

// gram+normalize fused (measured ~4us): one block per row i; f_i staged in
// LDS; int dots exact; writes normalized value straight to d_out.
__global__ void __launch_bounds__(256) gram_k(const unsigned int* __restrict__ feats,
                                              const float* __restrict__ diag,
                                              float* __restrict__ out) {
    __shared__ unsigned int s_fi[N];
    int i = blockIdx.x, t = threadIdx.x;
    int lane = t & 63, w = t >> 6;
    ((uint4*)s_fi)[t] = ((const uint4*)(feats + (size_t)i * N))[t];
    __syncthreads();
    float di = diag[i];
    for (int jj = 0; jj < 16; ++jj) {
        int j = w * 16 + jj;
        const uint4* fj = (const uint4*)(feats + (size_t)j * N);
        const uint4* fi = (const uint4*)s_fi;
        int s = 0;
#pragma unroll
        for (int k = 0; k < 4; ++k) {
            uint4 vb = fj[lane + k * 64];
            uint4 va = fi[lane + k * 64];
            s += (int)(va.x * vb.x) + (int)(va.y * vb.y)
               + (int)(va.z * vb.z) + (int)(va.w * vb.w);
        }
#pragma unroll
        for (int off = 32; off > 0; off >>= 1) s += __shfl_down(s, off);
        if (lane == 0) out[i * B + j] = (float)s / sqrtf(di * diag[j]);
    }
}

extern "C" void kernel_launch(void* const* d_in, const int* in_sizes, int n_in,
                              void* d_out, int out_size, void* d_ws, size_t ws_size,
                              hipStream_t stream) {
    const int*   esrc = (const int*)d_in[0];
    const int*   edst = (const int*)d_in[1];
    const int*   lab0 = (const int*)d_in[2];
    const float* hw   = (const float*)d_in[3];

    char* ws = (char*)d_ws;
    unsigned int* feats = (unsigned int*)(ws + FEATS_OFF);
    float*        diag  = (float*)(ws + DIAG_OFF);

    wl_mega_k<<<B, 1024, 0, stream>>>(esrc, edst, lab0, hw, feats, diag);
    gram_k<<<B, 256, 0, stream>>>(feats, diag, (float*)d_out);
}

// Round 22
// 111.754 us; speedup vs baseline: 1.1871x; 1.1871x over previous
//
#include <hip/hip_runtime.h>

#define B 64
#define N 1024
#define E 16384
#define WPR 32          // words per adjacency row = N/32
#define NITER 5
#define CSR_SLOTS (E + N)   // even-aligned per-node alloc: <=1 pad slot/node
#define CH_ROWS 384
#define CH_WORDS (CH_ROWS * WPR)    // 12288 u32 = 48 KB chunk
#define NCHUNK 3

// ---- workspace layout (bytes) ---- (NO memset: feats/diag fully stored
// before any read; harness 0xAA poison harmless)
#define FEATS_OFF 0
#define DIAG_OFF  ((size_t)B * N * 4)

// R22 = exact R20 revert (measured best: 111.8us, absmax 0). R21's two
// "shavings" both regressed (mega 42->62us): same-address LDS atomicMin/Max
// in the hot loop serializes (2nd confirmation after R10), and self-cleaning
// capture doubles LDS ops (load+store pairs). R20's plain barrier + w0-shfl
// combine is the tested optimum across 18 structural variants.
__global__ void __launch_bounds__(1024) wl_mega_k(const int* __restrict__ src,
                                                  const int* __restrict__ dstp,
                                                  const int* __restrict__ lab0,
                                                  const float* __restrict__ hw,
                                                  unsigned int* __restrict__ feats,
                                                  float* __restrict__ diag) {
    __shared__ union {
        unsigned int chunk[CH_WORDS];               // Phase A1: 48KB bitmask tile
        struct {
            unsigned short nbr[CSR_SLOTS];          // Phase A2/B: 34.8KB CSR
            struct {                                // Phase B: rank arrays 16KB
                int hist[N];
                int scan[N];
                float grp[N];
                int flag[N];
            } pb;
        } s;
    } u;
    __shared__ int s_lab[N + 2];                    // +sentinel slot (=0)
    __shared__ unsigned int s_feats[N];
    __shared__ int s_wsum[16];
    __shared__ int s_kp[16];
    __shared__ float s_mn[16], s_mx[16];
    __shared__ float s_gmn, s_gmx;
    __shared__ int s_K;
    __shared__ int s_anytie;
    int b = blockIdx.x, t = threadIdx.x;
    int lane = t & 63, w = t >> 6;

    // ---- Phase A0: edges + labels to registers/LDS ----
    const int* sg = src + (size_t)b * E;
    const int* dg_ = dstp + (size_t)b * E;
    int es[16], ed[16];
#pragma unroll
    for (int k = 0; k < 16; ++k) {                  // coalesced, 1 block/graph
        es[k] = sg[t + k * 1024];
        ed[k] = dg_[t + k * 1024];
    }
    int l0 = lab0[(size_t)b * N + t];
    s_lab[t] = l0;
    s_feats[t] = 0;
    if (t == 0) { s_lab[N] = 0; s_anytie = 0; }
    __syncthreads();                                        // P0
    // init label bincount (labels < 16) via ballot
#pragma unroll
    for (int v = 0; v < 16; ++v) {
        unsigned long long m = __ballot(l0 == v);
        if (lane == v) {
            int c = __popcll(m);
            if (c) atomicAdd(&s_feats[v], (unsigned)c);
        }
    }

    // ---- Phase A1: 3-chunk LDS bitmask build (swizzled), row -> r[8] ----
    uint4 r[8];
#pragma unroll 1
    for (int c = 0; c < NCHUNK; ++c) {
        int base = c * CH_ROWS;
#pragma unroll
        for (int k = 0; k < 3; ++k)                 // zero 48KB
            ((uint4*)u.chunk)[t + k * 1024] = make_uint4(0, 0, 0, 0);
        __syncthreads();                                    // C1
#pragma unroll
        for (int k = 0; k < 16; ++k) {
            int rr = es[k] - base;
            if ((unsigned)rr < (unsigned)CH_ROWS) {
                int wlog = ed[k] >> 5;                      // logical word 0..31
                int g = wlog >> 2;                          // logical group 0..7
                int p = (g + rr) & 7;                       // swizzled slot
                atomicOr(&u.chunk[rr * WPR + p * 4 + (wlog & 3)],
                         1u << (ed[k] & 31));
            }
        }
        __syncthreads();                                    // C2
        int rl = t - base;
        if ((unsigned)rl < (unsigned)CH_ROWS) {             // own row lives here
            const uint4* row4 = (const uint4*)(u.chunk + rl * WPR);
#pragma unroll
            for (int g = 0; g < 8; ++g)
                r[g] = row4[(g + rl) & 7];                  // conflict-free
        }
        __syncthreads();                                    // C3
    }

    // ---- Phase A2: deg/alloc/K/CSR starts + pack ----
    int dg = 0;
#pragma unroll
    for (int k = 0; k < 8; ++k)
        dg += __popc(r[k].x) + __popc(r[k].y) + __popc(r[k].z) + __popc(r[k].w);
    int alloc = (dg + 1) & ~1;                      // even per-node CSR alloc

    int f = alloc;                                  // wave scan of alloc
#pragma unroll
    for (int d2 = 1; d2 < 64; d2 <<= 1) {
        int v = __shfl_up(f, d2);
        if (lane >= d2) f += v;
    }
    int km = dg;
#pragma unroll
    for (int o = 32; o > 0; o >>= 1) km = max(km, __shfl_down(km, o));
    if (lane == 63) s_wsum[w] = f;
    if (lane == 0)  s_kp[w] = km;
    __syncthreads();                                        // A1
    if (w == 0) {                                   // wave0 shfl combine
        int orig = (lane < 16) ? s_wsum[lane] : 0;
        int v = orig;
#pragma unroll
        for (int d2 = 1; d2 < 16; d2 <<= 1) {
            int uu = __shfl_up(v, d2);
            if (lane >= d2) v += uu;
        }
        if (lane < 16) s_wsum[lane] = v - orig;     // exclusive wave base
        int kk = (lane < 16) ? s_kp[lane] : 0;
#pragma unroll
        for (int m2 = 8; m2 >= 1; m2 >>= 1) kk = max(kk, __shfl_xor(kk, m2));
        if (lane == 0) s_K = kk;
    }
    __syncthreads();                                        // A2
    int start = (f - alloc) + s_wsum[w];            // even => u32-aligned
    u.s.pb.hist[t] = 0;                             // aliases chunk: re-init
    u.s.pb.flag[t] = 0;

    // pack own row's set bits ONCE -> u16 list; pad odd deg with sentinel N
    {
        int idx = start;
#pragma unroll
        for (int k = 0; k < 8; ++k) {
            unsigned int wv[4] = { r[k].x, r[k].y, r[k].z, r[k].w };
#pragma unroll
            for (int c2 = 0; c2 < 4; ++c2) {
                unsigned int word = wv[c2];
                int bb = (k * 4 + c2) << 5;
                while (word) {
                    int j = __ffs(word) - 1;
                    word &= word - 1;
                    u.s.nbr[idx++] = (unsigned short)(bb + j);
                }
            }
        }
        if (dg & 1) u.s.nbr[idx] = (unsigned short)N;   // sentinel -> adds 0
    }
    float Kf = (float)s_K;
    float w0 = hw[0], w1 = hw[1];
    int pairs = alloc >> 1;
    int pstart = start >> 1;
    __syncthreads();                                        // A3

    // ---- Phase B: 5 WL iterations (R12-proven machinery) ----
    for (int it = 0; it < NITER; ++it) {
        int s = 0;
        const unsigned int* nbr32 = (const unsigned int*)u.s.nbr;
        for (int k = 0; k < pairs; ++k) {
            unsigned int pr = nbr32[pstart + k];
            s += s_lab[pr & 0xFFFFu] + s_lab[pr >> 16];
        }
        float t1 = __fmul_rn(__fmul_rn(Kf, w0), (float)s_lab[t]);
        float t2 = __fmul_rn(w1, __fsub_rn(__fadd_rn((float)s, (float)dg), Kf));
        float h  = __fadd_rn(t1, t2);

        float mn = h, mx = h;
#pragma unroll
        for (int o = 32; o > 0; o >>= 1) {
            mn = fminf(mn, __shfl_down(mn, o));
            mx = fmaxf(mx, __shfl_down(mx, o));
        }
        if (lane == 0) { s_mn[w] = mn; s_mx[w] = mx; }
        __syncthreads();                                    // B1
        if (w == 0) {                                // wave0 shfl combine
            float a = (lane < 16) ? s_mn[lane] : 3.4e38f;
            float c = (lane < 16) ? s_mx[lane] : -3.4e38f;
#pragma unroll
            for (int m2 = 8; m2 >= 1; m2 >>= 1) {
                a = fminf(a, __shfl_xor(a, m2));
                c = fmaxf(c, __shfl_xor(c, m2));
            }
            if (lane == 0) { s_gmn = a; s_gmx = c; }
        }
        __syncthreads();                                    // B2
        float fmn = s_gmn;
        float span = s_gmx - fmn;
        float scale = (span > 0.f) ? (1023.0f / span) : 0.f;
        int bucket = min((int)((h - fmn) * scale), 1023);   // order-preserving
        int off_in = atomicAdd(&u.s.pb.hist[bucket], 1);
        __syncthreads();                                    // B3

        f = u.s.pb.hist[t];
#pragma unroll
        for (int d2 = 1; d2 < 64; d2 <<= 1) {
            int v = __shfl_up(f, d2);
            if (lane >= d2) f += v;
        }
        if (lane == 63) s_wsum[w] = f;
        __syncthreads();                                    // B4
        if (w == 0) {                                // wave0 shfl combine
            int orig = (lane < 16) ? s_wsum[lane] : 0;
            int v = orig;
#pragma unroll
            for (int d2 = 1; d2 < 16; d2 <<= 1) {
                int uu = __shfl_up(v, d2);
                if (lane >= d2) v += uu;
            }
            if (lane < 16) s_wsum[lane] = v - orig;  // exclusive
        }
        __syncthreads();                                    // B5
        u.s.pb.scan[t] = f + s_wsum[w];
        __syncthreads();                                    // B6

        int bs = u.s.pb.scan[bucket] - u.s.pb.hist[bucket];
        int be = u.s.pb.scan[bucket];
        u.s.pb.grp[bs + off_in] = h;
        __syncthreads();                                    // B7

        int c = bs;                 // lower buckets strictly less (monotone map)
        int eq = 0;
        for (int k = bs; k < be; ++k) {
            float g = u.s.pb.grp[k];
            c += (g < h);
            eq += (g == h);
        }
        if (eq > 1) s_anytie = it + 1;  // sentinel: stale iters self-invalidate
        u.s.pb.hist[t] = 0;             // re-zero for next iter
        __syncthreads();                                    // B8

        int rank;
        if (s_anytie != it + 1) {
            rank = c;                   // distinct keys: c IS the dense rank
            s_lab[t] = rank;
            s_feats[rank] += 1u;        // permutation -> conflict-free
        } else {
            u.s.pb.flag[c] = 1;         // class start (same class -> same c)
            __syncthreads();                                // T1
            int f2 = u.s.pb.flag[t];
#pragma unroll
            for (int d2 = 1; d2 < 64; d2 <<= 1) {
                int v = __shfl_up(f2, d2);
                if (lane >= d2) f2 += v;
            }
            if (lane == 63) s_wsum[w] = f2;
            __syncthreads();                                // T2
            if (w == 0) {                            // wave0 shfl combine
                int orig = (lane < 16) ? s_wsum[lane] : 0;
                int v = orig;
#pragma unroll
                for (int d2 = 1; d2 < 16; d2 <<= 1) {
                    int uu = __shfl_up(v, d2);
                    if (lane >= d2) v += uu;
                }
                if (lane < 16) s_wsum[lane] = v - orig;
            }
            __syncthreads();                                // T3
            u.s.pb.scan[t] = f2 + s_wsum[w];
            u.s.pb.flag[t] = 0;         // own flag consumed above
            __syncthreads();                                // T4
            rank = u.s.pb.scan[c] - 1;
            s_lab[t] = rank;
            atomicAdd(&s_feats[rank], 1u);
        }
        __syncthreads();                                    // B9
    }

    // ---- Phase C: feats out + fused diag[b] (int exact) ----
    unsigned int fv = s_feats[t];
    feats[(size_t)b * N + t] = fv;
    int sq = (int)(fv * fv);
#pragma unroll
    for (int o = 32; o > 0; o >>= 1) sq += __shfl_down(sq, o);
    if (lane == 0) s_wsum[w] = sq;
    __syncthreads();
    if (t == 0) {
        int tot = 0;
#pragma unroll
        for (int k = 0; k < 16; ++k) tot += s_wsum[k];
        diag[b] = (float)tot;
    }
}

// gram+normalize fused (measured ~4us): one block per row i; f_i staged in
// LDS; int dots exact; writes normalized value straight to d_out.
__global__ void __launch_bounds__(256) gram_k(const unsigned int* __restrict__ feats,
                                              const float* __restrict__ diag,
                                              float* __restrict__ out) {
    __shared__ unsigned int s_fi[N];
    int i = blockIdx.x, t = threadIdx.x;
    int lane = t & 63, w = t >> 6;
    ((uint4*)s_fi)[t] = ((const uint4*)(feats + (size_t)i * N))[t];
    __syncthreads();
    float di = diag[i];
    for (int jj = 0; jj < 16; ++jj) {
        int j = w * 16 + jj;
        const uint4* fj = (const uint4*)(feats + (size_t)j * N);
        const uint4* fi = (const uint4*)s_fi;
        int s = 0;
#pragma unroll
        for (int k = 0; k < 4; ++k) {
            uint4 vb = fj[lane + k * 64];
            uint4 va = fi[lane + k * 64];
            s += (int)(va.x * vb.x) + (int)(va.y * vb.y)
               + (int)(va.z * vb.z) + (int)(va.w * vb.w);
        }
#pragma unroll
        for (int off = 32; off > 0; off >>= 1) s += __shfl_down(s, off);
        if (lane == 0) out[i * B + j] = (float)s / sqrtf(di * diag[j]);
    }
}

extern "C" void kernel_launch(void* const* d_in, const int* in_sizes, int n_in,
                              void* d_out, int out_size, void* d_ws, size_t ws_size,
                              hipStream_t stream) {
    const int*   esrc = (const int*)d_in[0];
    const int*   edst = (const int*)d_in[1];
    const int*   lab0 = (const int*)d_in[2];
    const float* hw   = (const float*)d_in[3];

    char* ws = (char*)d_ws;
    unsigned int* feats = (unsigned int*)(ws + FEATS_OFF);
    float*        diag  = (float*)(ws + DIAG_OFF);

    wl_mega_k<<<B, 1024, 0, stream>>>(esrc, edst, lab0, hw, feats, diag);
    gram_k<<<B, 256, 0, stream>>>(feats, diag, (float*)d_out);
}